// Round 9
// baseline (148.936 us; speedup 1.0000x reference)
//
#include <hip/hip_runtime.h>
#include <math.h>

#define LN 8      // layers
#define NRBF 256
#define FD 16
#define OUTD 3
#define KC (-0.72134752044f)   // -0.5 * log2(e)

typedef __attribute__((ext_vector_type(8))) short short8;    // 8 x bf16
typedef __attribute__((ext_vector_type(4))) float floatx4;
typedef __attribute__((ext_vector_type(2))) float floatx2;

__device__ __forceinline__ short f2bf(float f) {
    unsigned u = __builtin_bit_cast(unsigned, f);
    u += 0x7fffu + ((u >> 16) & 1u);          // RNE
    return (short)(u >> 16);
}

// 16x16x32 layouts, nt-MAJOR (one n-tile's full j-chain contiguous):
//   PKB: short8 entry g = nt*512 + j*64 + lane   (8 KB per nt, 128 KB total)
//        lane l: n = nt*16+(l&15), kq = l>>4; elem e: k = kq*8+e,
//        feature f = kq*4+(e>>1); e even -> KC*A_f ; e odd -> -2*KC*A_f*C_f
//   EPI: float4 entry nt*128 + j*16 + (n&15) = {W'0, W'1, W'2, 0}  (2 KB per nt)
//        W'o = W[o][j*256+n] * exp2(KC * t3prefix_j[n])

__global__ __launch_bounds__(256) void prep(
    const float* __restrict__ centers, const float* __restrict__ betas,
    const float* __restrict__ W, short* __restrict__ PKB, float* __restrict__ EPI)
{
    __shared__ float ls[LN * 32];
    int blk = blockIdx.x;
    int tid = threadIdx.x;
    if (blk < 32) {
        int g    = blk * 256 + tid;        // = nt*512 + j*64 + lane (linear)
        int lane = g & 63;
        int j    = (g >> 6) & 7;
        int nt   = g >> 9;
        int n    = nt * 16 + (lane & 15);
        int kq   = lane >> 4;
        size_t base = ((size_t)(j * NRBF + n)) * FD + kq * 4;
        float4 bq = *(const float4*)(betas + base);
        float4 cq = *(const float4*)(centers + base);
        float a0 = KC * __expf(bq.x), a1 = KC * __expf(bq.y);
        float a2 = KC * __expf(bq.z), a3 = KC * __expf(bq.w);
        short8 v;
        v[0] = f2bf(a0); v[1] = f2bf(-2.0f * a0 * cq.x);
        v[2] = f2bf(a1); v[3] = f2bf(-2.0f * a1 * cq.y);
        v[4] = f2bf(a2); v[5] = f2bf(-2.0f * a2 * cq.z);
        v[6] = f2bf(a3); v[7] = f2bf(-2.0f * a3 * cq.w);
        *((short8*)(PKB + (size_t)g * 8)) = v;
    } else {
        int jj = tid >> 5;                  // 0..7
        int nl = tid & 31;
        int n  = (blk - 32) * 32 + nl;
        const float* bp = betas   + ((size_t)(jj * NRBF + n)) * FD;
        const float* cp = centers + ((size_t)(jj * NRBF + n)) * FD;
        float s = 0.f;
#pragma unroll
        for (int q = 0; q < 4; ++q) {
            float4 bq = *(const float4*)(bp + q * 4);
            float4 cq = *(const float4*)(cp + q * 4);
            s = fmaf(__expf(bq.x) * cq.x, cq.x, s);
            s = fmaf(__expf(bq.y) * cq.y, cq.y, s);
            s = fmaf(__expf(bq.z) * cq.z, cq.z, s);
            s = fmaf(__expf(bq.w) * cq.w, cq.w, s);
        }
        ls[jj * 32 + nl] = s;
        __syncthreads();
        float t3 = 0.f;
        for (int j2 = 0; j2 <= jj; ++j2) t3 += ls[j2 * 32 + nl];
        float E = __builtin_amdgcn_exp2f(KC * t3);
        float4 e;
        e.x = W[0 * (LN * NRBF) + jj * NRBF + n] * E;
        e.y = W[1 * (LN * NRBF) + jj * NRBF + n] * E;
        e.z = W[2 * (LN * NRBF) + jj * NRBF + n] * E;
        e.w = 0.f;
        ((float4*)EPI)[((size_t)(n >> 4) * 128) + jj * 16 + (n & 15)] = e;
    }
}

// build an A-fragment: elem e even -> x_f^2, odd -> x_f  (f = kq*4 + e>>1)
// NOTE: macro parameter must NOT be named x/y/z/w (member-access capture!)
#define CVT(dst, vv)  do {                                         \
        short8 f_;                                                 \
        f_[0] = f2bf((vv).x * (vv).x); f_[1] = f2bf((vv).x);       \
        f_[2] = f2bf((vv).y * (vv).y); f_[3] = f2bf((vv).y);       \
        f_[4] = f2bf((vv).z * (vv).z); f_[5] = f2bf((vv).z);       \
        f_[6] = f2bf((vv).w * (vv).w); f_[7] = f2bf((vv).w);       \
        (dst) = f_; } while (0)

// One wave owns a 16-sample tile x all 256 n x 8 layers, nt-OUTER / j-INNER
// with the one-j-lag pipeline (exps of layer j-1 run on accp while MFMA j
// flies). NO LDS STAGING: PKB+EPI total 160 KB and are L2-resident (R8:
// FETCH_SIZE = feats only). pk/ep fragments are read directly from L2 with
// plain global loads -- this deletes the per-CU LDS pipe cost (~21 us), all
// 16 barriers + vmcnt(0) drains per wave, and the STAGE address VALU
// (guide common-mistake #7: never LDS-stage L2-fit data, m169). Waves are
// now fully independent; fill against the ~34 us VALU-issue floor is the
// only remaining variable.
//
// REGISTER DISCIPLINE (rounds 2-8 post-mortems):
//  - nt-loop MUST be unroll 1 (scheduler hoist -> spill churn, R3/R4).
//  - j-loop MUST be fully unrolled (runtime j -> dyn-indexed reg arrays, R5).
//  - launch_bounds must NOT request min-waves (arch/acc split spill, R2/R3).
//  - spill sentinel: FETCH ~26MB / WRITE ~1.2MB. GB-scale => scratch churn.
//  - L2-residency sentinel: FETCH jump of ~+800MB => PKB re-reads miss L2.
__global__ __launch_bounds__(256) void rbf_mfma(
    const float* __restrict__ feats, const short* __restrict__ PKB,
    const float* __restrict__ EPI, const float* __restrict__ bias,
    float* __restrict__ out, int B)
{
    int tid  = threadIdx.x;
    int lane = tid & 63;
    int w    = tid >> 6;
    int ntile = (B + 15) >> 4;
    int tile = blockIdx.x * 4 + w;
    bool tvalid = (tile < ntile);
    if (!tvalid) tile = ntile - 1;        // duplicate work, no store
    int b0 = tile * 16;
    int m  = lane & 15;                   // sample-in-tile (A-row), D-col = n16
    int kq = lane >> 4;
    int brow = b0 + m; if (brow >= B) brow = B - 1;
    const float* xrow = feats + (size_t)brow * (LN * FD) + kq * 4;

    const short8* pkb8 = (const short8*)PKB;       // entry index = g
    const float4* epi4 = (const float4*)EPI;

// exps + projection for one layer (4 rows); o2 packed pairwise
#define EXPPROJ(accv, ev)                                          \
    do {                                                           \
        floatx2 exy_ = { (ev).x, (ev).y };                         \
        floatx2 ezz_ = { (ev).z, (ev).z };                         \
        float rv0_ = __builtin_amdgcn_exp2f((accv)[0]);            \
        float rv1_ = __builtin_amdgcn_exp2f((accv)[1]);            \
        float rv2_ = __builtin_amdgcn_exp2f((accv)[2]);            \
        float rv3_ = __builtin_amdgcn_exp2f((accv)[3]);            \
        o01[0] += (floatx2){rv0_, rv0_} * exy_;                    \
        o01[1] += (floatx2){rv1_, rv1_} * exy_;                    \
        o01[2] += (floatx2){rv2_, rv2_} * exy_;                    \
        o01[3] += (floatx2){rv3_, rv3_} * exy_;                    \
        oz[0]  += (floatx2){rv0_, rv1_} * ezz_;                    \
        oz[1]  += (floatx2){rv2_, rv3_} * ezz_;                    \
    } while (0)

    // A-fragments for all 8 layers (32 VGPRs), built once, STATIC index only
    short8 af[LN];
#pragma unroll
    for (int j = 0; j < LN; ++j) {
        float4 xa = *(const float4*)(xrow + j * FD);
        CVT(af[j], xa);
    }

    floatx2 o01[4];   // per-row {sum*W'0, sum*W'1}
    floatx2 oz[2];    // rows packed pairwise for W'2
#pragma unroll
    for (int r = 0; r < 4; ++r) o01[r] = (floatx2){0.f, 0.f};
    oz[0] = (floatx2){0.f, 0.f}; oz[1] = (floatx2){0.f, 0.f};

#pragma unroll 1
    for (int nt = 0; nt < 16; ++nt) {
        const short8* pb = pkb8 + (size_t)nt * 512 + lane;   // + j*64 (imm)
        const float4* eb = epi4 + (size_t)nt * 128 + m;      // + j*16 (imm)

        floatx4 acc = (floatx4){0.f, 0.f, 0.f, 0.f};
        floatx4 accp;   // one-j-lag snapshot (written before first read)

#pragma unroll
        for (int j = 0; j < LN; ++j) {
            short8 bf = pb[j * 64];       // L2-resident, coalesced 16B/lane
            acc = __builtin_amdgcn_mfma_f32_16x16x32_bf16(af[j], bf, acc, 0, 0, 0);
            if (j > 0) {                  // finish layer j-1 while MFMA j flies
                float4 e = eb[(j - 1) * 16];
                EXPPROJ(accp, e);
            }
            accp = acc;                   // snapshot after MFMA j completes
        }
        {   // tail: layer 7
            float4 e = eb[7 * 16];
            EXPPROJ(accp, e);
        }
    }
#undef EXPPROJ

    // reduce over the 16 n-lanes (xor 1,2,4,8 stays within kq group)
    float oacc[12];
#pragma unroll
    for (int r = 0; r < 4; ++r) {
        oacc[r * 3 + 0] = o01[r].x;
        oacc[r * 3 + 1] = o01[r].y;
        oacc[r * 3 + 2] = (r & 1) ? oz[r >> 1].y : oz[r >> 1].x;
    }
#pragma unroll
    for (int i = 0; i < 12; ++i) {
        oacc[i] += __shfl_xor(oacc[i], 1);
        oacc[i] += __shfl_xor(oacc[i], 2);
        oacc[i] += __shfl_xor(oacc[i], 4);
        oacc[i] += __shfl_xor(oacc[i], 8);
    }

    if (tvalid && m < OUTD) {
        float bv = bias[m];
#pragma unroll
        for (int r = 0; r < 4; ++r) {
            int row = b0 + kq * 4 + r;     // D-row = (lane>>4)*4 + reg
            if (row < B) out[(size_t)row * OUTD + m] = oacc[r * 3 + m] + bv;
        }
    }
}

extern "C" void kernel_launch(void* const* d_in, const int* in_sizes, int n_in,
                              void* d_out, int out_size, void* d_ws, size_t ws_size,
                              hipStream_t stream) {
    // inputs: 0=x (UNUSED by reference), 1=feats, 2=centers, 3=betas, 4=W, 5=b
    const float* feats   = (const float*)d_in[1];
    const float* centers = (const float*)d_in[2];
    const float* betas   = (const float*)d_in[3];
    const float* W       = (const float*)d_in[4];
    const float* bias    = (const float*)d_in[5];
    float* out = (float*)d_out;
    int B = in_sizes[1] / (LN * FD);

    short* PKB = (short*)d_ws;                       // 65536 shorts = 128 KB
    float* EPI = (float*)((char*)d_ws + 65536 * 2);  // 8192 floats = 32 KB

    prep<<<40, 256, 0, stream>>>(centers, betas, W, PKB, EPI);

    int tiles  = (B + 15) / 16;
    int blocks = (tiles + 3) / 4;
    rbf_mfma<<<blocks, 256, 0, stream>>>(feats, PKB, EPI, bias, out, B);
}

// Round 10
// 140.224 us; speedup vs baseline: 1.0621x; 1.0621x over previous
//
#include <hip/hip_runtime.h>
#include <math.h>

#define LN 8      // layers
#define NRBF 256
#define FD 16
#define OUTD 3
#define KC (-0.72134752044f)   // -0.5 * log2(e)

typedef __attribute__((ext_vector_type(8))) short short8;    // 8 x bf16
typedef __attribute__((ext_vector_type(4))) float floatx4;
typedef __attribute__((ext_vector_type(2))) float floatx2;

__device__ __forceinline__ short f2bf(float f) {
    unsigned u = __builtin_bit_cast(unsigned, f);
    u += 0x7fffu + ((u >> 16) & 1u);          // RNE
    return (short)(u >> 16);
}

// 16x16x32 layouts, nt-MAJOR (one n-tile's full j-chain contiguous):
//   PKB: short8 entry g = nt*512 + j*64 + lane   (8 KB per nt, 128 KB total)
//        lane l: n = nt*16+(l&15), kq = l>>4; elem e: k = kq*8+e,
//        feature f = kq*4+(e>>1); e even -> KC*A_f ; e odd -> -2*KC*A_f*C_f
//   EPI: float4 entry nt*128 + j*16 + (n&15) = {W'0, W'1, W'2, 0}  (2 KB per nt)
//        W'o = W[o][j*256+n] * exp2(KC * t3prefix_j[n])

__global__ __launch_bounds__(256) void prep(
    const float* __restrict__ centers, const float* __restrict__ betas,
    const float* __restrict__ W, short* __restrict__ PKB, float* __restrict__ EPI)
{
    __shared__ float ls[LN * 32];
    int blk = blockIdx.x;
    int tid = threadIdx.x;
    if (blk < 32) {
        int g    = blk * 256 + tid;        // = nt*512 + j*64 + lane (linear)
        int lane = g & 63;
        int j    = (g >> 6) & 7;
        int nt   = g >> 9;
        int n    = nt * 16 + (lane & 15);
        int kq   = lane >> 4;
        size_t base = ((size_t)(j * NRBF + n)) * FD + kq * 4;
        float4 bq = *(const float4*)(betas + base);
        float4 cq = *(const float4*)(centers + base);
        float a0 = KC * __expf(bq.x), a1 = KC * __expf(bq.y);
        float a2 = KC * __expf(bq.z), a3 = KC * __expf(bq.w);
        short8 v;
        v[0] = f2bf(a0); v[1] = f2bf(-2.0f * a0 * cq.x);
        v[2] = f2bf(a1); v[3] = f2bf(-2.0f * a1 * cq.y);
        v[4] = f2bf(a2); v[5] = f2bf(-2.0f * a2 * cq.z);
        v[6] = f2bf(a3); v[7] = f2bf(-2.0f * a3 * cq.w);
        *((short8*)(PKB + (size_t)g * 8)) = v;
    } else {
        int jj = tid >> 5;                  // 0..7
        int nl = tid & 31;
        int n  = (blk - 32) * 32 + nl;
        const float* bp = betas   + ((size_t)(jj * NRBF + n)) * FD;
        const float* cp = centers + ((size_t)(jj * NRBF + n)) * FD;
        float s = 0.f;
#pragma unroll
        for (int q = 0; q < 4; ++q) {
            float4 bq = *(const float4*)(bp + q * 4);
            float4 cq = *(const float4*)(cp + q * 4);
            s = fmaf(__expf(bq.x) * cq.x, cq.x, s);
            s = fmaf(__expf(bq.y) * cq.y, cq.y, s);
            s = fmaf(__expf(bq.z) * cq.z, cq.z, s);
            s = fmaf(__expf(bq.w) * cq.w, cq.w, s);
        }
        ls[jj * 32 + nl] = s;
        __syncthreads();
        float t3 = 0.f;
        for (int j2 = 0; j2 <= jj; ++j2) t3 += ls[j2 * 32 + nl];
        float E = __builtin_amdgcn_exp2f(KC * t3);
        float4 e;
        e.x = W[0 * (LN * NRBF) + jj * NRBF + n] * E;
        e.y = W[1 * (LN * NRBF) + jj * NRBF + n] * E;
        e.z = W[2 * (LN * NRBF) + jj * NRBF + n] * E;
        e.w = 0.f;
        ((float4*)EPI)[((size_t)(n >> 4) * 128) + jj * 16 + (n & 15)] = e;
    }
}

// build an A-fragment: elem e even -> x_f^2, odd -> x_f  (f = kq*4 + e>>1)
// NOTE: macro parameter must NOT be named x/y/z/w (member-access capture!)
#define CVT(dst, vv)  do {                                         \
        short8 f_;                                                 \
        f_[0] = f2bf((vv).x * (vv).x); f_[1] = f2bf((vv).x);       \
        f_[2] = f2bf((vv).y * (vv).y); f_[3] = f2bf((vv).y);       \
        f_[4] = f2bf((vv).z * (vv).z); f_[5] = f2bf((vv).z);       \
        f_[6] = f2bf((vv).w * (vv).w); f_[7] = f2bf((vv).w);       \
        (dst) = f_; } while (0)

// One wave owns a 16-sample tile x all 256 n x 8 layers. nt staged in CHUNKS
// OF 2; per j the wave runs TWO independent MFMA prefix chains (accA, accB)
// interleaved, each with its own one-j-lag exp pipeline. Rationale: VALU-busy
// time is invariant ~31us across R0/R6/R7/R8/R9; duration = 31us / fill.
// R8 (single chain) filled 54% -- the single 8-deep MFMA dep chain left the
// wave issue-starved during ds_read/MFMA latency. Two chains double the
// independent VALU work per chain-link and halve barrier count.
//
// REGISTER DISCIPLINE (rounds 2-9 post-mortems):
//  - chunk-loop MUST be unroll 1 (scheduler hoist -> spill churn, R3/R4).
//  - j-loop MUST be fully unrolled (runtime j -> dyn-indexed reg arrays, R5).
//  - launch_bounds must NOT request min-waves (arch/acc split spill, R2/R3).
//  - spill sentinel: FETCH ~26MB / WRITE ~1.2MB. GB-scale => scratch churn.
//  - L2-direct operand reads regress (R9): MFMA operands want LDS latency.
__global__ __launch_bounds__(256) void rbf_mfma(
    const float* __restrict__ feats, const short* __restrict__ PKB,
    const float* __restrict__ EPI, const float* __restrict__ bias,
    float* __restrict__ out, int B)
{
    __shared__ short8 pk_s[2][1024];   // 2 buf x (2 nt x 512) = 32 KB
    __shared__ float4 ep_s[2][256];    // 2 buf x (2 nt x 128) = 8 KB

    int tid  = threadIdx.x;
    int lane = tid & 63;
    int w    = tid >> 6;
    int ntile = (B + 15) >> 4;
    int tile = blockIdx.x * 4 + w;
    bool tvalid = (tile < ntile);
    if (!tvalid) tile = ntile - 1;        // duplicate work, no store
    int b0 = tile * 16;
    int m  = lane & 15;                   // sample-in-tile (A-row), D-col = n16
    int kq = lane >> 4;
    int brow = b0 + m; if (brow >= B) brow = B - 1;
    const float* xrow = feats + (size_t)brow * (LN * FD) + kq * 4;

// stage chunk c (nt = 2c, 2c+1): 16 KB pk (4 loads/thread) + 4 KB ep (1/thread)
#define STAGE(buf, c)                                                           \
    do {                                                                        \
        _Pragma("unroll")                                                       \
        for (int i = 0; i < 4; ++i) {                                           \
            const short* gp = PKB + ((size_t)(c) * 1024 + (w * 4 + i) * 64 + lane) * 8; \
            __builtin_amdgcn_global_load_lds(                                   \
                (const __attribute__((address_space(1))) void*)gp,              \
                (__attribute__((address_space(3))) void*)&pk_s[buf][(w * 4 + i) * 64], \
                16, 0, 0);                                                      \
        }                                                                       \
        const float* ge = EPI + ((size_t)(c) * 256 + w * 64 + lane) * 4;        \
        __builtin_amdgcn_global_load_lds(                                       \
            (const __attribute__((address_space(1))) void*)ge,                  \
            (__attribute__((address_space(3))) void*)&ep_s[buf][w * 64],        \
            16, 0, 0);                                                          \
    } while (0)

// exps + projection for one layer (4 rows); o2 packed pairwise
#define EXPPROJ(accv, ev)                                          \
    do {                                                           \
        floatx2 exy_ = { (ev).x, (ev).y };                         \
        floatx2 ezz_ = { (ev).z, (ev).z };                         \
        float rv0_ = __builtin_amdgcn_exp2f((accv)[0]);            \
        float rv1_ = __builtin_amdgcn_exp2f((accv)[1]);            \
        float rv2_ = __builtin_amdgcn_exp2f((accv)[2]);            \
        float rv3_ = __builtin_amdgcn_exp2f((accv)[3]);            \
        o01[0] += (floatx2){rv0_, rv0_} * exy_;                    \
        o01[1] += (floatx2){rv1_, rv1_} * exy_;                    \
        o01[2] += (floatx2){rv2_, rv2_} * exy_;                    \
        o01[3] += (floatx2){rv3_, rv3_} * exy_;                    \
        oz[0]  += (floatx2){rv0_, rv1_} * ezz_;                    \
        oz[1]  += (floatx2){rv2_, rv3_} * ezz_;                    \
    } while (0)

    STAGE(0, 0);   // issue first LDS fill; hides under the af-build below

    // A-fragments for all 8 layers (32 VGPRs), built once, STATIC index only
    short8 af[LN];
#pragma unroll
    for (int j = 0; j < LN; ++j) {
        float4 xa = *(const float4*)(xrow + j * FD);
        CVT(af[j], xa);
    }

    floatx2 o01[4];   // per-row {sum*W'0, sum*W'1} (summed over ALL n)
    floatx2 oz[2];    // rows packed pairwise for W'2
#pragma unroll
    for (int r = 0; r < 4; ++r) o01[r] = (floatx2){0.f, 0.f};
    oz[0] = (floatx2){0.f, 0.f}; oz[1] = (floatx2){0.f, 0.f};

    __syncthreads();

#pragma unroll 1
    for (int c = 0; c < 8; ++c) {         // chunk = 2 n-tiles
        int cur = c & 1;
        if (c < 7) STAGE(cur ^ 1, c + 1);

        floatx4 accA = (floatx4){0.f, 0.f, 0.f, 0.f};
        floatx4 accB = (floatx4){0.f, 0.f, 0.f, 0.f};
        floatx4 accpA, accpB;   // one-j-lag snapshots (written before read)

#pragma unroll
        for (int j = 0; j < LN; ++j) {
            short8 bfA = pk_s[cur][j * 64 + lane];
            short8 bfB = pk_s[cur][512 + j * 64 + lane];
            accA = __builtin_amdgcn_mfma_f32_16x16x32_bf16(af[j], bfA, accA, 0, 0, 0);
            accB = __builtin_amdgcn_mfma_f32_16x16x32_bf16(af[j], bfB, accB, 0, 0, 0);
            if (j > 0) {                  // finish layer j-1 on both chains
                float4 eA = ep_s[cur][(j - 1) * 16 + m];
                EXPPROJ(accpA, eA);
                float4 eB = ep_s[cur][128 + (j - 1) * 16 + m];
                EXPPROJ(accpB, eB);
            }
            accpA = accA;                 // snapshots after MFMA j
            accpB = accB;
        }
        {   // tail: layer 7 on both chains
            float4 eA = ep_s[cur][7 * 16 + m];
            EXPPROJ(accpA, eA);
            float4 eB = ep_s[cur][128 + 7 * 16 + m];
            EXPPROJ(accpB, eB);
        }
        __syncthreads();
    }
#undef STAGE
#undef EXPPROJ

    // reduce over the 16 n-lanes (xor 1,2,4,8 stays within kq group)
    float oacc[12];
#pragma unroll
    for (int r = 0; r < 4; ++r) {
        oacc[r * 3 + 0] = o01[r].x;
        oacc[r * 3 + 1] = o01[r].y;
        oacc[r * 3 + 2] = (r & 1) ? oz[r >> 1].y : oz[r >> 1].x;
    }
#pragma unroll
    for (int i = 0; i < 12; ++i) {
        oacc[i] += __shfl_xor(oacc[i], 1);
        oacc[i] += __shfl_xor(oacc[i], 2);
        oacc[i] += __shfl_xor(oacc[i], 4);
        oacc[i] += __shfl_xor(oacc[i], 8);
    }

    if (tvalid && m < OUTD) {
        float bv = bias[m];
#pragma unroll
        for (int r = 0; r < 4; ++r) {
            int row = b0 + kq * 4 + r;     // D-row = (lane>>4)*4 + reg
            if (row < B) out[(size_t)row * OUTD + m] = oacc[r * 3 + m] + bv;
        }
    }
}

extern "C" void kernel_launch(void* const* d_in, const int* in_sizes, int n_in,
                              void* d_out, int out_size, void* d_ws, size_t ws_size,
                              hipStream_t stream) {
    // inputs: 0=x (UNUSED by reference), 1=feats, 2=centers, 3=betas, 4=W, 5=b
    const float* feats   = (const float*)d_in[1];
    const float* centers = (const float*)d_in[2];
    const float* betas   = (const float*)d_in[3];
    const float* W       = (const float*)d_in[4];
    const float* bias    = (const float*)d_in[5];
    float* out = (float*)d_out;
    int B = in_sizes[1] / (LN * FD);

    short* PKB = (short*)d_ws;                       // 65536 shorts = 128 KB
    float* EPI = (float*)((char*)d_ws + 65536 * 2);  // 8192 floats = 32 KB

    prep<<<40, 256, 0, stream>>>(centers, betas, W, PKB, EPI);

    int tiles  = (B + 15) / 16;
    int blocks = (tiles + 3) / 4;
    rbf_mfma<<<blocks, 256, 0, stream>>>(feats, PKB, EPI, bias, out, B);
}